// Round 1
// baseline (920.565 us; speedup 1.0000x reference)
//
#include <hip/hip_runtime.h>
#include <float.h>

// Problem constants (VisualDict): N tokens, K codes, D dim, fp32.
constexpr int N = 16384;
constexpr int K = 8192;
constexpr int D = 256;

constexpr int BM = 128;    // rows per block
constexpr int BN = 128;    // codes per k-tile
constexpr int DK = 32;     // d-chunk staged in LDS
constexpr int KSPLIT = 8;  // K split across blockIdx.y
constexpr int KCHUNK = K / KSPLIT;  // 1024
constexpr int LDX = BM + 4;  // 132: keeps float4 LDS reads 16B-aligned, <=2-way conflicts
constexpr int LDE = BN + 4;

// ---- row sum-of-squares: one wave per row, D=256 = 64 lanes x float4 ----
__global__ void vq_rowsq(const float* __restrict__ A, float* __restrict__ out) {
    int row = blockIdx.x;
    int lane = threadIdx.x;  // 64
    float4 v = ((const float4*)(A + (size_t)row * D))[lane];
    float s = v.x * v.x + v.y * v.y + v.z * v.z + v.w * v.w;
    #pragma unroll
    for (int o = 32; o > 0; o >>= 1) s += __shfl_down(s, o);
    if (lane == 0) out[row] = s;
}

// ---- main: fused score GEMM + per-row argmin over a K-chunk ----
__global__ __launch_bounds__(256) void vq_main(
    const float* __restrict__ X, const float* __restrict__ E,
    const float* __restrict__ xsq, const float* __restrict__ esq,
    float* __restrict__ pmin, int* __restrict__ pidx) {
    __shared__ float sx[DK * LDX];
    __shared__ float se[DK * LDE];

    const int t = threadIdx.x;
    const int row0 = blockIdx.x * BM;
    const int kbeg = blockIdx.y * KCHUNK;

    const int lane = t & 63, wave = t >> 6;
    const int lm = lane >> 3, ln = lane & 7;
    const int mf = (wave >> 1) * 64 + lm * 8;  // frag row base within tile
    const int nf = (wave & 1) * 64 + ln * 8;   // frag code base within tile

    float xs[8];
    #pragma unroll
    for (int i = 0; i < 8; i++) xs[i] = xsq[row0 + mf + i];

    float rmin[8];
    int ridx[8];
    #pragma unroll
    for (int i = 0; i < 8; i++) { rmin[i] = FLT_MAX; ridx[i] = 0; }

    // staging coords: 256 threads load 128 rows x 32 cols (float4 each, x4 row groups)
    const int sm = t >> 3;         // 0..31
    const int sd = (t & 7) * 4;    // 0,4,..,28

    for (int kt = kbeg; kt < kbeg + KCHUNK; kt += BN) {
        float acc[8][8];
        #pragma unroll
        for (int i = 0; i < 8; i++)
            #pragma unroll
            for (int j = 0; j < 8; j++) acc[i][j] = 0.0f;

        for (int d0 = 0; d0 < D; d0 += DK) {
            __syncthreads();
            #pragma unroll
            for (int r = 0; r < 4; r++) {
                int row = sm + 32 * r;
                float4 v = *(const float4*)(X + (size_t)(row0 + row) * D + d0 + sd);
                sx[(sd + 0) * LDX + row] = v.x;
                sx[(sd + 1) * LDX + row] = v.y;
                sx[(sd + 2) * LDX + row] = v.z;
                sx[(sd + 3) * LDX + row] = v.w;
                float4 w = *(const float4*)(E + (size_t)(kt + row) * D + d0 + sd);
                se[(sd + 0) * LDE + row] = w.x;
                se[(sd + 1) * LDE + row] = w.y;
                se[(sd + 2) * LDE + row] = w.z;
                se[(sd + 3) * LDE + row] = w.w;
            }
            __syncthreads();
            #pragma unroll
            for (int d = 0; d < DK; d++) {
                float4 a0 = *(const float4*)(sx + d * LDX + mf);
                float4 a1 = *(const float4*)(sx + d * LDX + mf + 4);
                float4 b0 = *(const float4*)(se + d * LDE + nf);
                float4 b1 = *(const float4*)(se + d * LDE + nf + 4);
                float a[8] = {a0.x, a0.y, a0.z, a0.w, a1.x, a1.y, a1.z, a1.w};
                float b[8] = {b0.x, b0.y, b0.z, b0.w, b1.x, b1.y, b1.z, b1.w};
                #pragma unroll
                for (int i = 0; i < 8; i++)
                    #pragma unroll
                    for (int j = 0; j < 8; j++) acc[i][j] += a[i] * b[j];
            }
        }

        float es[8];
        #pragma unroll
        for (int j = 0; j < 8; j++) es[j] = esq[kt + nf + j];
        #pragma unroll
        for (int i = 0; i < 8; i++) {
            #pragma unroll
            for (int j = 0; j < 8; j++) {
                // match reference rounding order: (x_sq + e_sq) - 2*dot
                float s = (xs[i] + es[j]) - 2.0f * acc[i][j];
                if (s < rmin[i]) { rmin[i] = s; ridx[i] = kt + nf + j; }  // ascending k: strict < keeps first min
            }
        }
    }

    // cross-thread argmin per row: 16 candidates per row (2 wn x 8 ln), via LDS overlay
    __syncthreads();
    float* redm = sx;           // 128*16 = 2048 floats (sx holds 4224)
    int* redi = (int*)se;       // 2048 ints
    const int c = (wave & 1) * 8 + ln;
    #pragma unroll
    for (int i = 0; i < 8; i++) {
        int r = (wave >> 1) * 64 + lm * 8 + i;
        redm[r * 16 + c] = rmin[i];
        redi[r * 16 + c] = ridx[i];
    }
    __syncthreads();
    if (t < BM) {
        float best = redm[t * 16];
        int bi = redi[t * 16];
        #pragma unroll
        for (int c2 = 1; c2 < 16; c2++) {
            float v = redm[t * 16 + c2];
            int id = redi[t * 16 + c2];
            if (v < best || (v == best && id < bi)) { best = v; bi = id; }
        }
        pmin[(size_t)(row0 + t) * KSPLIT + blockIdx.y] = best;
        pidx[(size_t)(row0 + t) * KSPLIT + blockIdx.y] = bi;
    }
}

// ---- final: reduce KSPLIT partials, write index (as float) + gather embed row ----
__global__ void vq_final(const float* __restrict__ E, const float* __restrict__ pmin,
                         const int* __restrict__ pidx, float* __restrict__ out_q,
                         float* __restrict__ out_idx) {
    int row = blockIdx.x;
    int lane = threadIdx.x;  // 64
    float best = pmin[(size_t)row * KSPLIT];
    int bi = pidx[(size_t)row * KSPLIT];
    #pragma unroll
    for (int s = 1; s < KSPLIT; s++) {
        float v = pmin[(size_t)row * KSPLIT + s];
        int id = pidx[(size_t)row * KSPLIT + s];
        if (v < best || (v == best && id < bi)) { best = v; bi = id; }
    }
    if (lane == 0) out_idx[row] = (float)bi;
    float4 v = ((const float4*)(E + (size_t)bi * D))[lane];
    ((float4*)(out_q + (size_t)row * D))[lane] = v;
}

extern "C" void kernel_launch(void* const* d_in, const int* in_sizes, int n_in,
                              void* d_out, int out_size, void* d_ws, size_t ws_size,
                              hipStream_t stream) {
    const float* X = (const float*)d_in[0];  // [N, D]
    const float* E = (const float*)d_in[1];  // [K, D]
    float* out_q = (float*)d_out;                     // [N, D]
    float* out_idx = (float*)d_out + (size_t)N * D;   // [N] written as float

    // workspace layout: esq[K] | xsq[N] | pmin[N*KSPLIT] | pidx[N*KSPLIT]  (~1.1 MB)
    float* esq = (float*)d_ws;
    float* xsq = esq + K;
    float* pmin = xsq + N;
    int* pidx = (int*)(pmin + (size_t)N * KSPLIT);

    vq_rowsq<<<K, 64, 0, stream>>>(E, esq);
    vq_rowsq<<<N, 64, 0, stream>>>(X, xsq);
    dim3 grid(N / BM, KSPLIT);
    vq_main<<<grid, 256, 0, stream>>>(X, E, xsq, esq, pmin, pidx);
    vq_final<<<N, 64, 0, stream>>>(E, pmin, pidx, out_q, out_idx);
}

// Round 2
// 283.335 us; speedup vs baseline: 3.2490x; 3.2490x over previous
//
#include <hip/hip_runtime.h>
#include <float.h>
#include <limits.h>

constexpr int N = 16384;
constexpr int K = 8192;
constexpr int D = 256;

typedef _Float16 half8_t __attribute__((ext_vector_type(8)));
typedef float float4_t __attribute__((ext_vector_type(4)));

// ---------------- shared: row sum-of-squares (one wave per row) ----------------
__global__ void vq_rowsq(const float* __restrict__ A, float* __restrict__ out) {
    int row = blockIdx.x;
    int lane = threadIdx.x;  // 64
    float4 v = ((const float4*)(A + (size_t)row * D))[lane];
    float s = v.x * v.x + v.y * v.y + v.z * v.z + v.w * v.w;
    #pragma unroll
    for (int o = 32; o > 0; o >>= 1) s += __shfl_down(s, o);
    if (lane == 0) out[row] = s;
}

// =======================================================================
// FAST PATH: f16 split-2 MFMA GEMM + fused top-2 argmin + fp32 rescore
// =======================================================================

// Pre-tile + split fp32 -> (hi,lo) f16, swizzled chunk layout.
// chunk = 8 dims (16B). region(rt,ds) = 128 rows x 4 quads = 512 chunks, laid
// out at slot = lr*4 + (quad ^ ((lr>>1)&3)) so ds_read_b128 fragment reads are
// bank-conflict-free(2-way max) AND global_load_lds staging is lane-linear.
__global__ void vq_prep(const float* __restrict__ src, _Float16* __restrict__ h,
                        _Float16* __restrict__ l, int nchunks) {
    int c = blockIdx.x * 256 + threadIdx.x;
    if (c >= nchunks) return;
    int r = c >> 5;          // source row
    int q8 = c & 31;         // 8-dim chunk within row
    int ds = q8 >> 2, quad = q8 & 3;
    int rt = r >> 7, lr = r & 127;
    int slot = lr * 4 + (quad ^ ((lr >> 1) & 3));
    size_t dst = ((size_t)(rt * 8 + ds) * 512 + (size_t)slot) * 8;
    const float4* s4 = (const float4*)(src + (size_t)r * D + q8 * 8);
    float4 v0 = s4[0], v1 = s4[1];
    float x[8] = {v0.x, v0.y, v0.z, v0.w, v1.x, v1.y, v1.z, v1.w};
    half8_t hh, ll;
    #pragma unroll
    for (int i = 0; i < 8; i++) {
        _Float16 hi = (_Float16)x[i];
        hh[i] = hi;
        ll[i] = (_Float16)(x[i] - (float)hi);  // x - hi exact in fp32
    }
    *(half8_t*)(h + dst) = hh;
    *(half8_t*)(l + dst) = ll;
}

__device__ __forceinline__ void ldg_lds16(const _Float16* g, _Float16* l) {
    __builtin_amdgcn_global_load_lds(
        (const __attribute__((address_space(1))) unsigned int*)g,
        (__attribute__((address_space(3))) unsigned int*)l, 16, 0, 0);
}

constexpr int CS = 4;  // K-split: 512 blocks = 2/CU

// block: 256 thr = 4 waves, tile 128 rows x 128 codes, waves 2x2 (64x64 each)
// LDS: [Xh|Xl|Eh|El] regions of 8KB (512 chunks) per d-step, single-buffered.
__global__ __launch_bounds__(256, 2) void vq_mfma(
    const _Float16* __restrict__ Xh, const _Float16* __restrict__ Xl,
    const _Float16* __restrict__ Eh, const _Float16* __restrict__ El,
    const float* __restrict__ esq, int2* __restrict__ pcand) {
    __shared__ _Float16 lds[16384];  // 32KB

    const int t = threadIdx.x, w = t >> 6, lane = t & 63;
    const int rt = blockIdx.x;  // row tile 0..127
    const int cs = blockIdx.y;  // code split 0..3
    const int r15 = lane & 15, quad = lane >> 4;
    const int sw = quad ^ ((r15 >> 1) & 3);
    // fragment chunk-slot bases (16B units); + mt*64 / + nt*64 per tile
    const int abase = ((w >> 1) * 64 + r15) * 4 + sw;
    const int bbase = ((w & 1) * 64 + r15) * 4 + sw;

    float best[16];
    int bidx[16];
    #pragma unroll
    for (int i = 0; i < 16; i++) { best[i] = FLT_MAX; bidx[i] = INT_MAX; }

    const half8_t* Xh_l = (const half8_t*)lds;
    const half8_t* Xl_l = (const half8_t*)(lds + 4096);
    const half8_t* Eh_l = (const half8_t*)(lds + 8192);
    const half8_t* El_l = (const half8_t*)(lds + 12288);

    for (int kt2 = 0; kt2 < 16; kt2++) {
        const int ct = cs * 16 + kt2;   // global code tile 0..63
        const int code0 = ct * 128;

        float4_t acc[4][4];
        #pragma unroll
        for (int mt = 0; mt < 4; mt++)
            #pragma unroll
            for (int nt = 0; nt < 4; nt++) acc[mt][nt] = {0.f, 0.f, 0.f, 0.f};

        for (int ds = 0; ds < 8; ds++) {
            __syncthreads();
            {  // wave w stages region w (8 x 1KB lane-linear chunks)
                size_t xoff = ((size_t)rt * 8 + ds) * 4096;
                size_t eoff = ((size_t)ct * 8 + ds) * 4096;
                const _Float16* s = (w == 0) ? Xh + xoff
                                  : (w == 1) ? Xl + xoff
                                  : (w == 2) ? Eh + eoff
                                             : El + eoff;
                _Float16* d = lds + w * 4096;
                #pragma unroll
                for (int i = 0; i < 8; i++)
                    ldg_lds16(s + (size_t)(i * 64 + lane) * 8, d + i * 512);
            }
            __syncthreads();

            half8_t Ah[4], Al[4], Bh[4], Bl[4];
            #pragma unroll
            for (int mt = 0; mt < 4; mt++) {
                Ah[mt] = Xh_l[abase + mt * 64];
                Al[mt] = Xl_l[abase + mt * 64];
            }
            #pragma unroll
            for (int nt = 0; nt < 4; nt++) {
                Bh[nt] = Eh_l[bbase + nt * 64];
                Bl[nt] = El_l[bbase + nt * 64];
            }
            #pragma unroll
            for (int mt = 0; mt < 4; mt++)
                #pragma unroll
                for (int nt = 0; nt < 4; nt++) {
                    acc[mt][nt] = __builtin_amdgcn_mfma_f32_16x16x32_f16(
                        Ah[mt], Bh[nt], acc[mt][nt], 0, 0, 0);
                    acc[mt][nt] = __builtin_amdgcn_mfma_f32_16x16x32_f16(
                        Ah[mt], Bl[nt], acc[mt][nt], 0, 0, 0);
                    acc[mt][nt] = __builtin_amdgcn_mfma_f32_16x16x32_f16(
                        Al[mt], Bh[nt], acc[mt][nt], 0, 0, 0);
                }
        }

        // epilogue: s = esq[code] - 2*dot  (x_sq is argmin-invariant)
        #pragma unroll
        for (int nt = 0; nt < 4; nt++) {
            const int code = code0 + (w & 1) * 64 + nt * 16 + r15;
            const float eq = esq[code];
            #pragma unroll
            for (int mt = 0; mt < 4; mt++)
                #pragma unroll
                for (int rg = 0; rg < 4; rg++) {
                    float s = fmaf(-2.f, acc[mt][nt][rg], eq);
                    int sl = mt * 4 + rg;
                    if (s < best[sl]) { best[sl] = s; bidx[sl] = code; }
                }
        }
    }

    // block reduction: per row, top-2 over 32 contributors
    __syncthreads();
    float* smin = (float*)lds;           // [32][128]
    int* sidx = (int*)(lds + 8192);      // [32][128]
    const int cont = (w & 1) * 16 + r15;
    #pragma unroll
    for (int sl = 0; sl < 16; sl++) {
        int row = (w >> 1) * 64 + (sl >> 2) * 16 + quad * 4 + (sl & 3);
        smin[cont * 128 + row] = best[sl];
        sidx[cont * 128 + row] = bidx[sl];
    }
    __syncthreads();
    if (t < 128) {
        float m1 = FLT_MAX, m2 = FLT_MAX;
        int i1 = INT_MAX, i2 = INT_MAX;
        for (int c = 0; c < 32; c++) {
            float v = smin[c * 128 + t];
            int id = sidx[c * 128 + t];
            if (v < m1 || (v == m1 && id < i1)) {
                m2 = m1; i2 = i1; m1 = v; i1 = id;
            } else if (v < m2 || (v == m2 && id < i2)) {
                m2 = v; i2 = id;
            }
        }
        pcand[(size_t)(rt * 128 + t) * CS + cs] = make_int2(i1, i2);
    }
}

__device__ __forceinline__ float wave_sum(float v) {
    #pragma unroll
    for (int o = 1; o < 64; o <<= 1) v += __shfl_xor(v, o);
    return v;
}

// rescore all 8 candidates in exact fp32 (reference formula/order), gather.
__global__ void vq_rescore(const float* __restrict__ X, const float* __restrict__ E,
                           const int2* __restrict__ pcand, float* __restrict__ out_q,
                           float* __restrict__ out_idx) {
    int row = blockIdx.x * 4 + (threadIdx.x >> 6);
    int lane = threadIdx.x & 63;
    float4 xv = ((const float4*)(X + (size_t)row * D))[lane];
    float xs = wave_sum(xv.x * xv.x + xv.y * xv.y + xv.z * xv.z + xv.w * xv.w);
    const int* cand = (const int*)(pcand + (size_t)row * CS);
    float bestv = FLT_MAX;
    int besti = INT_MAX;
    for (int c = 0; c < 2 * CS; c++) {
        int idx = cand[c];
        float4 ev = ((const float4*)(E + (size_t)idx * D))[lane];
        float dp = wave_sum(xv.x * ev.x + xv.y * ev.y + xv.z * ev.z + xv.w * ev.w);
        float eq = wave_sum(ev.x * ev.x + ev.y * ev.y + ev.z * ev.z + ev.w * ev.w);
        float s = (xs + eq) - 2.f * dp;
        if (s < bestv || (s == bestv && idx < besti)) { bestv = s; besti = idx; }
    }
    if (lane == 0) out_idx[row] = (float)besti;
    float4 bv = ((const float4*)(E + (size_t)besti * D))[lane];
    ((float4*)(out_q + (size_t)row * D))[lane] = bv;
}

// =======================================================================
// FALLBACK (proven R1 fp32 path) — used only if ws_size is too small
// =======================================================================
constexpr int BM = 128, BN = 128, DK = 32, KSPLIT = 8;
constexpr int KCHUNK = K / KSPLIT;
constexpr int LDX = BM + 4, LDE = BN + 4;

__global__ __launch_bounds__(256) void vq_main(
    const float* __restrict__ X, const float* __restrict__ E,
    const float* __restrict__ xsq, const float* __restrict__ esq,
    float* __restrict__ pmin, int* __restrict__ pidx) {
    __shared__ float sx[DK * LDX];
    __shared__ float se[DK * LDE];
    const int t = threadIdx.x;
    const int row0 = blockIdx.x * BM;
    const int kbeg = blockIdx.y * KCHUNK;
    const int lane = t & 63, wave = t >> 6;
    const int lm = lane >> 3, ln = lane & 7;
    const int mf = (wave >> 1) * 64 + lm * 8;
    const int nf = (wave & 1) * 64 + ln * 8;
    float xs[8];
    #pragma unroll
    for (int i = 0; i < 8; i++) xs[i] = xsq[row0 + mf + i];
    float rmin[8];
    int ridx[8];
    #pragma unroll
    for (int i = 0; i < 8; i++) { rmin[i] = FLT_MAX; ridx[i] = 0; }
    const int sm = t >> 3;
    const int sd = (t & 7) * 4;
    for (int kt = kbeg; kt < kbeg + KCHUNK; kt += BN) {
        float acc[8][8];
        #pragma unroll
        for (int i = 0; i < 8; i++)
            #pragma unroll
            for (int j = 0; j < 8; j++) acc[i][j] = 0.0f;
        for (int d0 = 0; d0 < D; d0 += DK) {
            __syncthreads();
            #pragma unroll
            for (int r = 0; r < 4; r++) {
                int row = sm + 32 * r;
                float4 v = *(const float4*)(X + (size_t)(row0 + row) * D + d0 + sd);
                sx[(sd + 0) * LDX + row] = v.x;
                sx[(sd + 1) * LDX + row] = v.y;
                sx[(sd + 2) * LDX + row] = v.z;
                sx[(sd + 3) * LDX + row] = v.w;
                float4 ww = *(const float4*)(E + (size_t)(kt + row) * D + d0 + sd);
                se[(sd + 0) * LDE + row] = ww.x;
                se[(sd + 1) * LDE + row] = ww.y;
                se[(sd + 2) * LDE + row] = ww.z;
                se[(sd + 3) * LDE + row] = ww.w;
            }
            __syncthreads();
            #pragma unroll
            for (int d = 0; d < DK; d++) {
                float4 a0 = *(const float4*)(sx + d * LDX + mf);
                float4 a1 = *(const float4*)(sx + d * LDX + mf + 4);
                float4 b0 = *(const float4*)(se + d * LDE + nf);
                float4 b1 = *(const float4*)(se + d * LDE + nf + 4);
                float a[8] = {a0.x, a0.y, a0.z, a0.w, a1.x, a1.y, a1.z, a1.w};
                float b[8] = {b0.x, b0.y, b0.z, b0.w, b1.x, b1.y, b1.z, b1.w};
                #pragma unroll
                for (int i = 0; i < 8; i++)
                    #pragma unroll
                    for (int j = 0; j < 8; j++) acc[i][j] += a[i] * b[j];
            }
        }
        float es[8];
        #pragma unroll
        for (int j = 0; j < 8; j++) es[j] = esq[kt + nf + j];
        #pragma unroll
        for (int i = 0; i < 8; i++)
            #pragma unroll
            for (int j = 0; j < 8; j++) {
                float s = (xs[i] + es[j]) - 2.0f * acc[i][j];
                if (s < rmin[i]) { rmin[i] = s; ridx[i] = kt + nf + j; }
            }
    }
    __syncthreads();
    float* redm = sx;
    int* redi = (int*)se;
    const int c = (wave & 1) * 8 + ln;
    #pragma unroll
    for (int i = 0; i < 8; i++) {
        int r = (wave >> 1) * 64 + lm * 8 + i;
        redm[r * 16 + c] = rmin[i];
        redi[r * 16 + c] = ridx[i];
    }
    __syncthreads();
    if (t < BM) {
        float bst = redm[t * 16];
        int bi = redi[t * 16];
        #pragma unroll
        for (int c2 = 1; c2 < 16; c2++) {
            float v = redm[t * 16 + c2];
            int id = redi[t * 16 + c2];
            if (v < bst || (v == bst && id < bi)) { bst = v; bi = id; }
        }
        pmin[(size_t)(row0 + t) * KSPLIT + blockIdx.y] = bst;
        pidx[(size_t)(row0 + t) * KSPLIT + blockIdx.y] = bi;
    }
}

__global__ void vq_final(const float* __restrict__ E, const float* __restrict__ pmin,
                         const int* __restrict__ pidx, float* __restrict__ out_q,
                         float* __restrict__ out_idx) {
    int row = blockIdx.x;
    int lane = threadIdx.x;
    float bst = pmin[(size_t)row * KSPLIT];
    int bi = pidx[(size_t)row * KSPLIT];
    #pragma unroll
    for (int s = 1; s < KSPLIT; s++) {
        float v = pmin[(size_t)row * KSPLIT + s];
        int id = pidx[(size_t)row * KSPLIT + s];
        if (v < bst || (v == bst && id < bi)) { bst = v; bi = id; }
    }
    if (lane == 0) out_idx[row] = (float)bi;
    float4 v = ((const float4*)(E + (size_t)bi * D))[lane];
    ((float4*)(out_q + (size_t)row * D))[lane] = v;
}

// =======================================================================
extern "C" void kernel_launch(void* const* d_in, const int* in_sizes, int n_in,
                              void* d_out, int out_size, void* d_ws, size_t ws_size,
                              hipStream_t stream) {
    const float* X = (const float*)d_in[0];  // [N, D]
    const float* E = (const float*)d_in[1];  // [K, D]
    float* out_q = (float*)d_out;
    float* out_idx = (float*)d_out + (size_t)N * D;

    // fast-path ws layout: Xh(8MB) Xl(8MB) Eh(4MB) El(4MB) esq(32KB) pcand(512KB)
    const size_t need = (size_t)24 * 1024 * 1024 + 32768 + 524288;
    if (ws_size >= need) {
        _Float16* Xh = (_Float16*)d_ws;
        _Float16* Xl = Xh + (size_t)N * D;
        _Float16* Eh = Xl + (size_t)N * D;
        _Float16* El = Eh + (size_t)K * D;
        float* esq = (float*)(El + (size_t)K * D);
        int2* pcand = (int2*)(esq + K);

        vq_rowsq<<<K, 64, 0, stream>>>(E, esq);
        vq_prep<<<(N * 32) / 256, 256, 0, stream>>>(X, Xh, Xl, N * 32);
        vq_prep<<<(K * 32) / 256, 256, 0, stream>>>(E, Eh, El, K * 32);
        dim3 grid(N / 128, CS);
        vq_mfma<<<grid, 256, 0, stream>>>(Xh, Xl, Eh, El, esq, pcand);
        vq_rescore<<<N / 4, 256, 0, stream>>>(X, E, pcand, out_q, out_idx);
    } else {
        float* esq = (float*)d_ws;
        float* xsq = esq + K;
        float* pmin = xsq + N;
        int* pidx = (int*)(pmin + (size_t)N * KSPLIT);
        vq_rowsq<<<K, 64, 0, stream>>>(E, esq);
        vq_rowsq<<<N, 64, 0, stream>>>(X, xsq);
        dim3 grid(N / BM, KSPLIT);
        vq_main<<<grid, 256, 0, stream>>>(X, E, xsq, esq, pmin, pidx);
        vq_final<<<N, 64, 0, stream>>>(E, pmin, pidx, out_q, out_idx);
    }
}